// Round 1
// baseline (372.644 us; speedup 1.0000x reference)
//
#include <hip/hip_runtime.h>

#define B_   32
#define S_   1024
#define K_   16
#define D_   32
#define NT1  128      // threads per knn block (= queries per block)
#define CAP  48       // per-thread LDS candidate buffer entries

// Stable insertion of (dn, jn) into ascending-sorted (dl, il).
// No-op if dn >= dl[15]. Ties keep the incumbent (earlier index) first.
__device__ __forceinline__ void insert16(float (&dl)[16], int (&il)[16],
                                         float dn, int jn) {
#pragma unroll
    for (int k = 15; k >= 1; --k) {
        bool c1 = dn < dl[k - 1];
        bool c2 = dn < dl[k];
        float nd = c1 ? dl[k - 1] : (c2 ? dn : dl[k]);
        int   ni = c1 ? il[k - 1] : (c2 ? jn : il[k]);
        dl[k] = nd;
        il[k] = ni;
    }
    bool c0 = dn < dl[0];
    dl[0] = c0 ? dn : dl[0];
    il[0] = c0 ? jn : il[0];
}

__global__ __launch_bounds__(NT1, 1)
void knn_kernel(const float* __restrict__ pos, int* __restrict__ idx_out) {
    __shared__ float4 spos[S_];            // 16 KB, padded xyz
    __shared__ uint2  buf[CAP][NT1];       // 48 KB, [entry][thread] -> conflict-free

    const int tid   = threadIdx.x;
    const int cloud = blockIdx.x >> 3;     // 8 blocks per cloud
    const int qbase = (blockIdx.x & 7) * NT1;
    const int base  = cloud * S_;

    // stage this cloud's positions into LDS
    for (int r = tid; r < S_; r += NT1) {
        const float* p = pos + (size_t)(base + r) * 3;
        spos[r] = make_float4(p[0], p[1], p[2], 0.0f);
    }
    __syncthreads();

    const int qi = qbase + tid;            // query index within cloud
    const float4 pi = spos[qi];
    const float pix = pi.x, piy = pi.y, piz = pi.z;

    float dl[16];
    int   il[16];
#pragma unroll
    for (int k = 0; k < 16; ++k) { dl[k] = 3.4e38f; il[k] = 0; }
    float w   = 3.4e38f;                   // current 16th-smallest (stale ok)
    int   cnt = 0;
    int   start = 0;

    for (int c = 0; c < 7; ++c) {          // chunk ends: 16,32,64,...,1024
        const int end = 16 << c;
#pragma unroll 8
        for (int j = start; j < end; ++j) {
            const float4 pj = spos[j];     // wave-uniform -> LDS broadcast
            // match numpy fp32 exactly: no fma contraction, (dx2+dy2)+dz2
            const float dx = __fsub_rn(pix, pj.x);
            const float dy = __fsub_rn(piy, pj.y);
            const float dz = __fsub_rn(piz, pj.z);
            const float d2 = __fadd_rn(
                __fadd_rn(__fmul_rn(dx, dx), __fmul_rn(dy, dy)),
                __fmul_rn(dz, dz));
            if (d2 < w) {                  // strict <: tie keeps earlier index
                if (cnt < CAP) {
                    buf[cnt][tid] = make_uint2(__float_as_uint(d2), (unsigned)j);
                    ++cnt;
                } else {
                    insert16(dl, il, d2, j);   // overflow fallback (≈never)
                }
            }
        }
        // drain this lane's buffer (entries in increasing j -> stable)
        for (int k = 0; k < cnt; ++k) {
            const uint2 e = buf[k][tid];
            insert16(dl, il, __uint_as_float(e.x), (int)e.y);
        }
        cnt = 0;
        w = dl[15];
        start = end;
    }

    const size_t orow = (size_t)(base + qi) * K_;
#pragma unroll
    for (int k = 0; k < 16; ++k)
        idx_out[orow + k] = base + il[k];  // store global neighbor index
}

// One float4 per thread: 16 lanes cover one (i,k) pair's 64-float row.
__global__ __launch_bounds__(256)
void out_kernel(const float* __restrict__ x, const float* __restrict__ pos,
                const float* __restrict__ Wm, const float* __restrict__ bv,
                const int* __restrict__ idx, float* __restrict__ out) {
    const int gid = blockIdx.x * 256 + threadIdx.x;   // = p*16 + r
    const int r = gid & 15;
    const int p = gid >> 4;                            // pair index in [0, N*K)
    const int j = idx[p];                              // global neighbor index

    const float4* x4   = (const float4*)x;
    float4*       out4 = (float4*)out;

    if (r < 8) {
        // channels 0..31: x_j  (x row = 8 float4, 128B aligned)
        out4[gid] = x4[j * 8 + r];
    } else {
        // channels 32..63: relu(feats @ W + b), 4 channels per lane
        const int i = p >> 4;                          // global query index
        const float pix = pos[i * 3 + 0], piy = pos[i * 3 + 1], piz = pos[i * 3 + 2];
        const float pjx = pos[j * 3 + 0], pjy = pos[j * 3 + 1], pjz = pos[j * 3 + 2];
        const float rx = pix - pjx, ry = piy - pjy, rz = piz - pjz;
        const float dist = sqrtf(rx * rx + ry * ry + rz * rz + 1e-12f);
        const float f[10] = {pix, piy, piz, pjx, pjy, pjz, rx, ry, rz, dist};

        const int c4 = r - 8;                          // float4 column block 0..7
        const float4* W4 = (const float4*)Wm;          // W[10][32] row = 8 float4
        float4 acc = ((const float4*)bv)[c4];
#pragma unroll
        for (int m = 0; m < 10; ++m) {
            const float4 wv = W4[m * 8 + c4];
            acc.x = fmaf(f[m], wv.x, acc.x);
            acc.y = fmaf(f[m], wv.y, acc.y);
            acc.z = fmaf(f[m], wv.z, acc.z);
            acc.w = fmaf(f[m], wv.w, acc.w);
        }
        acc.x = fmaxf(acc.x, 0.0f);
        acc.y = fmaxf(acc.y, 0.0f);
        acc.z = fmaxf(acc.z, 0.0f);
        acc.w = fmaxf(acc.w, 0.0f);
        out4[gid] = acc;
    }
}

extern "C" void kernel_launch(void* const* d_in, const int* in_sizes, int n_in,
                              void* d_out, int out_size, void* d_ws, size_t ws_size,
                              hipStream_t stream) {
    const float* x   = (const float*)d_in[0];
    const float* pos = (const float*)d_in[1];
    // d_in[2] = batch (unused: equal-size contiguous segments)
    const float* Wm  = (const float*)d_in[3];
    const float* bv  = (const float*)d_in[4];
    int*   idx = (int*)d_ws;                 // N*K ints = 2 MB scratch
    float* out = (float*)d_out;

    knn_kernel<<<B_ * 8, NT1, 0, stream>>>(pos, idx);

    const int total = (B_ * S_) * K_ * 16;   // one thread per float4 of output
    out_kernel<<<total / 256, 256, 0, stream>>>(x, pos, Wm, bv, idx, out);
}

// Round 2
// 94.627 us; speedup vs baseline: 3.9380x; 3.9380x over previous
//
#include <hip/hip_runtime.h>

typedef unsigned long long u64;
typedef unsigned int u32;

#define B_  32
#define S_  1024
#define K_  16
#define D_  32

#define NTK 256     // knn threads/block
#define QPB 32      // queries per block (NTK/8)
#define NSL 8       // slices (threads) per query
#define SLC 128     // candidates per slice

__device__ __forceinline__ u64 u64min(u64 a, u64 b) { return a < b ? a : b; }

// ascending bitonic sort of 16 u64 keys (fully unrolled, static indexing only)
__device__ __forceinline__ void sort16(u64 (&k)[16]) {
#pragma unroll
    for (int size = 2; size <= 16; size <<= 1) {
#pragma unroll
        for (int str = size >> 1; str > 0; str >>= 1) {
#pragma unroll
            for (int t = 0; t < 16; ++t) {
                const int p = t ^ str;
                if (p > t) {
                    const bool up = ((t & size) == 0);
                    const u64 a = k[t], b = k[p];
                    const bool sw = up ? (b < a) : (a < b);
                    k[t] = sw ? b : a;
                    k[p] = sw ? a : b;
                }
            }
        }
    }
}

// clean a bitonic 16-sequence into ascending order
__device__ __forceinline__ void clean16(u64 (&k)[16]) {
#pragma unroll
    for (int str = 8; str > 0; str >>= 1) {
#pragma unroll
        for (int t = 0; t < 16; ++t) {
            const int p = t ^ str;
            if (p > t) {
                const u64 a = k[t], b = k[p];
                const bool sw = (b < a);
                k[t] = sw ? b : a;
                k[p] = sw ? a : b;
            }
        }
    }
}

__global__ __launch_bounds__(NTK, 4)
void knn_kernel(const float* __restrict__ pos, int* __restrict__ idx_out) {
    __shared__ float4 spos[S_];             // 16 KB

    const int tid   = threadIdx.x;
    const int cloud = blockIdx.x >> 5;      // 32 blocks per cloud
    const int qbase = (blockIdx.x & 31) * QPB;
    const int base  = cloud * S_;

    for (int r = tid; r < S_; r += NTK) {
        const float* p = pos + (size_t)(base + r) * 3;
        spos[r] = make_float4(p[0], p[1], p[2], 0.0f);
    }
    __syncthreads();

    const int s  = tid & 7;                 // slice
    const int qi = qbase + (tid >> 3);      // query within cloud
    const float4 pi = spos[qi];
    const float pix = pi.x, piy = pi.y, piz = pi.z;

    const int jb = s * SLC;
    int ii = s;                             // rotated offset -> distinct banks across slices

    u64 key[16];

    // chunk 0: first 16 candidates form the initial sorted list
#pragma unroll
    for (int t = 0; t < 16; ++t) {
        const int j = jb + ii; ii = (ii + 1) & (SLC - 1);
        const float4 pj = spos[j];
        const float dx = __fsub_rn(pix, pj.x);
        const float dy = __fsub_rn(piy, pj.y);
        const float dz = __fsub_rn(piz, pj.z);
        const float d2 = __fadd_rn(
            __fadd_rn(__fmul_rn(dx, dx), __fmul_rn(dy, dy)), __fmul_rn(dz, dz));
        key[t] = ((u64)__float_as_uint(d2) << 32) | (u32)j;
    }
    sort16(key);

    // chunks 1..7: sort 16 new candidates, bitonic half-merge into running top-16
    for (int c = 1; c < 8; ++c) {
        u64 nk[16];
#pragma unroll
        for (int t = 0; t < 16; ++t) {
            const int j = jb + ii; ii = (ii + 1) & (SLC - 1);
            const float4 pj = spos[j];
            const float dx = __fsub_rn(pix, pj.x);
            const float dy = __fsub_rn(piy, pj.y);
            const float dz = __fsub_rn(piz, pj.z);
            const float d2 = __fadd_rn(
                __fadd_rn(__fmul_rn(dx, dx), __fmul_rn(dy, dy)), __fmul_rn(dz, dz));
            nk[t] = ((u64)__float_as_uint(d2) << 32) | (u32)j;
        }
        sort16(nk);
#pragma unroll
        for (int t = 0; t < 8; ++t) {
            const u64 a = key[t], b = nk[15 - t];
            const u64 c2 = key[15 - t], d = nk[t];
            key[t]      = u64min(a, b);
            key[15 - t] = u64min(c2, d);
        }
        clean16(key);
    }

    // butterfly merge of the 8 slice lists (lanes s, s^1, s^2, s^4 share a query)
#pragma unroll
    for (int r = 1; r <= 4; r <<= 1) {
        u64 nk[16];
#pragma unroll
        for (int t = 0; t < 16; ++t)
            nk[t] = (u64)__shfl_xor((unsigned long long)key[15 - t], r, 64);
        // nk[t] == partner_key[15-t]
#pragma unroll
        for (int t = 0; t < 8; ++t) {
            const u64 a = key[t], b = nk[t];
            const u64 c2 = key[15 - t], d = nk[15 - t];
            key[t]      = u64min(a, b);
            key[15 - t] = u64min(c2, d);
        }
        clean16(key);
    }

    if (s == 0) {
        int4* o4 = (int4*)(idx_out + (size_t)(base + qi) * K_);
#pragma unroll
        for (int t = 0; t < 4; ++t) {
            int4 v;
            v.x = base + (int)(u32)key[4 * t + 0];
            v.y = base + (int)(u32)key[4 * t + 1];
            v.z = base + (int)(u32)key[4 * t + 2];
            v.w = base + (int)(u32)key[4 * t + 3];
            o4[t] = v;
        }
    }
}

// 8 threads per (i,k) pair: thread r copies x_j float4 r AND computes enc channels 4r..4r+3.
__global__ __launch_bounds__(256)
void out_kernel(const float* __restrict__ x, const float* __restrict__ pos,
                const float* __restrict__ Wm, const float* __restrict__ bv,
                const int* __restrict__ idx, float* __restrict__ out) {
    const int t = blockIdx.x * 256 + threadIdx.x;   // t = p*8 + r
    const int r = t & 7;
    const int p = t >> 3;                            // pair index in [0, N*K)
    const int j = idx[p];                            // global neighbor index
    const int i = p >> 4;                            // global query index

    const float4* x4   = (const float4*)x;
    float4*       out4 = (float4*)out;

    // channels 0..31: x_j
    out4[(size_t)p * 16 + r] = x4[(size_t)j * 8 + r];

    // channels 32..63: relu(feats @ W + b)
    const float pix = pos[i * 3 + 0], piy = pos[i * 3 + 1], piz = pos[i * 3 + 2];
    const float pjx = pos[j * 3 + 0], pjy = pos[j * 3 + 1], pjz = pos[j * 3 + 2];
    const float rx = pix - pjx, ry = piy - pjy, rz = piz - pjz;
    const float dist = sqrtf(rx * rx + ry * ry + rz * rz + 1e-12f);
    const float f[10] = {pix, piy, piz, pjx, pjy, pjz, rx, ry, rz, dist};

    const float4* W4 = (const float4*)Wm;            // W[10][32]: row = 8 float4
    float4 acc = ((const float4*)bv)[r];
#pragma unroll
    for (int m = 0; m < 10; ++m) {
        const float4 wv = W4[m * 8 + r];
        acc.x = fmaf(f[m], wv.x, acc.x);
        acc.y = fmaf(f[m], wv.y, acc.y);
        acc.z = fmaf(f[m], wv.z, acc.z);
        acc.w = fmaf(f[m], wv.w, acc.w);
    }
    acc.x = fmaxf(acc.x, 0.0f);
    acc.y = fmaxf(acc.y, 0.0f);
    acc.z = fmaxf(acc.z, 0.0f);
    acc.w = fmaxf(acc.w, 0.0f);
    out4[(size_t)p * 16 + 8 + r] = acc;
}

extern "C" void kernel_launch(void* const* d_in, const int* in_sizes, int n_in,
                              void* d_out, int out_size, void* d_ws, size_t ws_size,
                              hipStream_t stream) {
    const float* x   = (const float*)d_in[0];
    const float* pos = (const float*)d_in[1];
    // d_in[2] = batch (unused: equal-size contiguous clouds)
    const float* Wm  = (const float*)d_in[3];
    const float* bv  = (const float*)d_in[4];
    int*   idx = (int*)d_ws;                 // N*K ints = 2 MB scratch
    float* out = (float*)d_out;

    knn_kernel<<<B_ * 32, NTK, 0, stream>>>(pos, idx);

    const int pairs = B_ * S_ * K_;          // 524288
    out_kernel<<<(pairs * 8) / 256, 256, 0, stream>>>(x, pos, Wm, bv, idx, out);
}

// Round 3
// 93.436 us; speedup vs baseline: 3.9882x; 1.0127x over previous
//
#include <hip/hip_runtime.h>

typedef unsigned long long u64;
typedef unsigned int u32;

#define B_  32
#define S_  1024
#define K_  16
#define D_  32

#define NTK 256     // knn threads/block
#define QPB 32      // queries per block (NTK/8)

__device__ __forceinline__ u64 u64min(u64 a, u64 b) { return a < b ? a : b; }

// ascending bitonic sort of 16 u64 keys (fully unrolled, static indexing only)
__device__ __forceinline__ void sort16(u64 (&k)[16]) {
#pragma unroll
    for (int size = 2; size <= 16; size <<= 1) {
#pragma unroll
        for (int str = size >> 1; str > 0; str >>= 1) {
#pragma unroll
            for (int t = 0; t < 16; ++t) {
                const int p = t ^ str;
                if (p > t) {
                    const bool up = ((t & size) == 0);
                    const u64 a = k[t], b = k[p];
                    const bool sw = up ? (b < a) : (a < b);
                    k[t] = sw ? b : a;
                    k[p] = sw ? a : b;
                }
            }
        }
    }
}

// ascending bitonic sort of 8 u64 keys
__device__ __forceinline__ void sort8(u64 (&k)[8]) {
#pragma unroll
    for (int size = 2; size <= 8; size <<= 1) {
#pragma unroll
        for (int str = size >> 1; str > 0; str >>= 1) {
#pragma unroll
            for (int t = 0; t < 8; ++t) {
                const int p = t ^ str;
                if (p > t) {
                    const bool up = ((t & size) == 0);
                    const u64 a = k[t], b = k[p];
                    const bool sw = up ? (b < a) : (a < b);
                    k[t] = sw ? b : a;
                    k[p] = sw ? a : b;
                }
            }
        }
    }
}

// clean a bitonic 16-sequence into ascending order
__device__ __forceinline__ void clean16(u64 (&k)[16]) {
#pragma unroll
    for (int str = 8; str > 0; str >>= 1) {
#pragma unroll
        for (int t = 0; t < 16; ++t) {
            const int p = t ^ str;
            if (p > t) {
                const u64 a = k[t], b = k[p];
                const bool sw = (b < a);
                k[t] = sw ? b : a;
                k[p] = sw ? a : b;
            }
        }
    }
}

__global__ __launch_bounds__(NTK, 5)
void knn_kernel(const float* __restrict__ pos, int* __restrict__ idx_out) {
    __shared__ float4 spos[S_];             // 16 KB

    const int tid   = threadIdx.x;
    const int cloud = blockIdx.x >> 5;      // 32 blocks per cloud
    const int qbase = (blockIdx.x & 31) * QPB;
    const int base  = cloud * S_;

    for (int r = tid; r < S_; r += NTK) {
        const float* p = pos + (size_t)(base + r) * 3;
        spos[r] = make_float4(p[0], p[1], p[2], 0.0f);
    }
    __syncthreads();

    const int s  = tid & 7;                 // slice: j = s (mod 8)
    const int qi = qbase + (tid >> 3);      // query within cloud
    const float4 pi = spos[qi];
    const float pix = pi.x, piy = pi.y, piz = pi.z;

    u64 key[16];
    int j = s;

    // first 16 candidates of the slice form the initial sorted list
#pragma unroll
    for (int t = 0; t < 16; ++t, j += 8) {
        const float4 pj = spos[j];          // offset folds to compile-time imm
        const float dx = __fsub_rn(pix, pj.x);
        const float dy = __fsub_rn(piy, pj.y);
        const float dz = __fsub_rn(piz, pj.z);
        const float d2 = __fadd_rn(
            __fadd_rn(__fmul_rn(dx, dx), __fmul_rn(dy, dy)), __fmul_rn(dz, dz));
        key[t] = ((u64)__float_as_uint(d2) << 32) | (u32)j;
    }
    sort16(key);

    // remaining 112 candidates in 14 chunks of 8: sort8 + half-merge + clean16
    for (int c = 0; c < 14; ++c) {
        u64 nk[8];
#pragma unroll
        for (int u = 0; u < 8; ++u, j += 8) {
            const float4 pj = spos[j];
            const float dx = __fsub_rn(pix, pj.x);
            const float dy = __fsub_rn(piy, pj.y);
            const float dz = __fsub_rn(piz, pj.z);
            const float d2 = __fadd_rn(
                __fadd_rn(__fmul_rn(dx, dx), __fmul_rn(dy, dy)), __fmul_rn(dz, dz));
            nk[u] = ((u64)__float_as_uint(d2) << 32) | (u32)j;
        }
        sort8(nk);
        // merge keep-16-smallest: equivalent to INF-padded bitonic half-merge
#pragma unroll
        for (int t = 0; t < 8; ++t)
            key[8 + t] = u64min(key[8 + t], nk[7 - t]);
        clean16(key);
    }

    // butterfly merge of the 8 slice lists (lanes s^1, s^2, s^4 share a query)
#pragma unroll
    for (int r = 1; r <= 4; r <<= 1) {
        u64 nk[16];
#pragma unroll
        for (int t = 0; t < 16; ++t)
            nk[t] = (u64)__shfl_xor((unsigned long long)key[15 - t], r, 64);
        // nk[t] == partner_key[15-t]
#pragma unroll
        for (int t = 0; t < 8; ++t) {
            const u64 a = key[t], b = nk[t];
            const u64 c2 = key[15 - t], d = nk[15 - t];
            key[t]      = u64min(a, b);
            key[15 - t] = u64min(c2, d);
        }
        clean16(key);
    }

    if (s == 0) {
        int4* o4 = (int4*)(idx_out + (size_t)(base + qi) * K_);
#pragma unroll
        for (int t = 0; t < 4; ++t) {
            int4 v;
            v.x = base + (int)(u32)key[4 * t + 0];
            v.y = base + (int)(u32)key[4 * t + 1];
            v.z = base + (int)(u32)key[4 * t + 2];
            v.w = base + (int)(u32)key[4 * t + 3];
            o4[t] = v;
        }
    }
}

// 8 threads per (i,k) pair: thread r copies x_j float4 r AND computes enc channels 4r..4r+3.
__global__ __launch_bounds__(256)
void out_kernel(const float* __restrict__ x, const float* __restrict__ pos,
                const float* __restrict__ Wm, const float* __restrict__ bv,
                const int* __restrict__ idx, float* __restrict__ out) {
    const int t = blockIdx.x * 256 + threadIdx.x;   // t = p*8 + r
    const int r = t & 7;
    const int p = t >> 3;                            // pair index in [0, N*K)
    const int j = idx[p];                            // global neighbor index
    const int i = p >> 4;                            // global query index

    const float4* x4   = (const float4*)x;
    float4*       out4 = (float4*)out;

    // channels 0..31: x_j
    out4[(size_t)p * 16 + r] = x4[(size_t)j * 8 + r];

    // channels 32..63: relu(feats @ W + b)
    const float pix = pos[i * 3 + 0], piy = pos[i * 3 + 1], piz = pos[i * 3 + 2];
    const float pjx = pos[j * 3 + 0], pjy = pos[j * 3 + 1], pjz = pos[j * 3 + 2];
    const float rx = pix - pjx, ry = piy - pjy, rz = piz - pjz;
    const float dist = sqrtf(rx * rx + ry * ry + rz * rz + 1e-12f);
    const float f[10] = {pix, piy, piz, pjx, pjy, pjz, rx, ry, rz, dist};

    const float4* W4 = (const float4*)Wm;            // W[10][32]: row = 8 float4
    float4 acc = ((const float4*)bv)[r];
#pragma unroll
    for (int m = 0; m < 10; ++m) {
        const float4 wv = W4[m * 8 + r];
        acc.x = fmaf(f[m], wv.x, acc.x);
        acc.y = fmaf(f[m], wv.y, acc.y);
        acc.z = fmaf(f[m], wv.z, acc.z);
        acc.w = fmaf(f[m], wv.w, acc.w);
    }
    acc.x = fmaxf(acc.x, 0.0f);
    acc.y = fmaxf(acc.y, 0.0f);
    acc.z = fmaxf(acc.z, 0.0f);
    acc.w = fmaxf(acc.w, 0.0f);
    out4[(size_t)p * 16 + 8 + r] = acc;
}

extern "C" void kernel_launch(void* const* d_in, const int* in_sizes, int n_in,
                              void* d_out, int out_size, void* d_ws, size_t ws_size,
                              hipStream_t stream) {
    const float* x   = (const float*)d_in[0];
    const float* pos = (const float*)d_in[1];
    // d_in[2] = batch (unused: equal-size contiguous clouds)
    const float* Wm  = (const float*)d_in[3];
    const float* bv  = (const float*)d_in[4];
    int*   idx = (int*)d_ws;                 // N*K ints = 2 MB scratch
    float* out = (float*)d_out;

    knn_kernel<<<B_ * 32, NTK, 0, stream>>>(pos, idx);

    const int pairs = B_ * S_ * K_;          // 524288
    out_kernel<<<(pairs * 8) / 256, 256, 0, stream>>>(x, pos, Wm, bv, idx, out);
}

// Round 4
// 65.892 us; speedup vs baseline: 5.6554x; 1.4180x over previous
//
#include <hip/hip_runtime.h>

typedef unsigned long long u64;
typedef unsigned int u32;

#define B_  32
#define S_  1024
#define K_  16

#define NTK 256     // knn threads/block
#define QPB 32      // queries per block (NTK/8)

// key = double whose bit pattern is (d2_f32_bits << 32) | j.
// d2 >= 0 -> high word in [0, 0x7F7FFFFF] -> positive finite double,
// so IEEE fmin/fmax (v_min_f64/v_max_f64) order keys exactly as u64.
__device__ __forceinline__ double pack_key(float d2, int j) {
    return __longlong_as_double(((u64)__float_as_uint(d2) << 32) | (u32)j);
}

// ascending compare-exchange: 2 VALU instrs
__device__ __forceinline__ void ce(double& a, double& b) {
    const double lo = fmin(a, b);
    const double hi = fmax(a, b);
    a = lo; b = hi;
}

// Batcher odd-even mergesort of 8 keys, 19 CE, depth 6, ascending
__device__ __forceinline__ void sort8(double (&k)[8]) {
    ce(k[0], k[1]); ce(k[2], k[3]); ce(k[4], k[5]); ce(k[6], k[7]);
    ce(k[0], k[2]); ce(k[1], k[3]); ce(k[4], k[6]); ce(k[5], k[7]);
    ce(k[1], k[2]); ce(k[5], k[6]);
    ce(k[0], k[4]); ce(k[1], k[5]); ce(k[2], k[6]); ce(k[3], k[7]);
    ce(k[2], k[4]); ce(k[3], k[5]);
    ce(k[1], k[2]); ce(k[3], k[4]); ce(k[5], k[6]);
}

// clean a bitonic 16-sequence into ascending order (4 stages, 32 CE)
__device__ __forceinline__ void clean16(double (&k)[16]) {
#pragma unroll
    for (int str = 8; str > 0; str >>= 1) {
#pragma unroll
        for (int t = 0; t < 16; ++t) {
            const int p = t ^ str;
            if (p > t) ce(k[t], k[p]);
        }
    }
}

__global__ __launch_bounds__(NTK, 4)
void knn_kernel(const float* __restrict__ pos, int* __restrict__ idx_out) {
    __shared__ float4 spos[S_];             // 16 KB

    const int tid   = threadIdx.x;
    const int cloud = blockIdx.x >> 5;      // 32 blocks per cloud
    const int qbase = (blockIdx.x & 31) * QPB;
    const int base  = cloud * S_;

    for (int r = tid; r < S_; r += NTK) {
        const float* p = pos + (size_t)(base + r) * 3;
        spos[r] = make_float4(p[0], p[1], p[2], 0.0f);
    }
    __syncthreads();

    const int s  = tid & 7;                 // slice: j = s (mod 8)
    const int qi = qbase + (tid >> 3);      // query within cloud
    const float4 pi = spos[qi];
    const float pix = pi.x, piy = pi.y, piz = pi.z;

    double key[16];
#pragma unroll
    for (int t = 0; t < 16; ++t)
        key[t] = __longlong_as_double(0x7FEFFFFFFFFFFFFFULL);  // > any real key

    const float4* sp = &spos[s];            // lane slice pointer, stride 8
    float4 buf[8];                          // software-pipelined chunk loads
#pragma unroll
    for (int u = 0; u < 8; ++u) buf[u] = sp[8 * u];

    int jlow = s;                           // global j of buf[0]
    for (int c = 0; c < 16; ++c) {          // 16 chunks x 8 candidates = 128
        double nk[8];
#pragma unroll
        for (int u = 0; u < 8; ++u) {
            // bit-exact numpy chain: no fma, (dx2+dy2)+dz2
            const float dx = __fsub_rn(pix, buf[u].x);
            const float dy = __fsub_rn(piy, buf[u].y);
            const float dz = __fsub_rn(piz, buf[u].z);
            const float d2 = __fadd_rn(
                __fadd_rn(__fmul_rn(dx, dx), __fmul_rn(dy, dy)),
                __fmul_rn(dz, dz));
            nk[u] = pack_key(d2, jlow + 8 * u);
        }
        if (c < 15) {                       // prefetch next chunk during sort
            sp += 64;
#pragma unroll
            for (int u = 0; u < 8; ++u) buf[u] = sp[8 * u];
        }
        jlow += 64;

        sort8(nk);
        // keep-16-smallest: INF-padded bitonic half-merge, then clean
#pragma unroll
        for (int t = 0; t < 8; ++t)
            key[8 + t] = fmin(key[8 + t], nk[7 - t]);
        clean16(key);
    }

    // butterfly merge of the 8 slice lists (lanes s^1, s^2, s^4 share a query)
#pragma unroll
    for (int r = 1; r <= 4; r <<= 1) {
        double nk[16];
#pragma unroll
        for (int t = 0; t < 16; ++t)
            nk[t] = __shfl_xor(key[15 - t], r, 64);  // reversed partner list
#pragma unroll
        for (int t = 0; t < 16; ++t)
            key[t] = fmin(key[t], nk[t]);            // stride-16 half-cleaner
        clean16(key);
    }

    if (s == 0) {
        int4* o4 = (int4*)(idx_out + (size_t)(base + qi) * K_);
#pragma unroll
        for (int t = 0; t < 4; ++t) {
            int4 v;
            v.x = base + (int)(u32)__double_as_longlong(key[4 * t + 0]);
            v.y = base + (int)(u32)__double_as_longlong(key[4 * t + 1]);
            v.z = base + (int)(u32)__double_as_longlong(key[4 * t + 2]);
            v.w = base + (int)(u32)__double_as_longlong(key[4 * t + 3]);
            o4[t] = v;
        }
    }
}

// 8 threads per (i,k) pair: thread r copies x_j float4 r AND computes enc channels 4r..4r+3.
__global__ __launch_bounds__(256)
void out_kernel(const float* __restrict__ x, const float* __restrict__ pos,
                const float* __restrict__ Wm, const float* __restrict__ bv,
                const int* __restrict__ idx, float* __restrict__ out) {
    const int t = blockIdx.x * 256 + threadIdx.x;   // t = p*8 + r
    const int r = t & 7;
    const int p = t >> 3;                            // pair index in [0, N*K)
    const int j = idx[p];                            // global neighbor index
    const int i = p >> 4;                            // global query index

    const float4* x4   = (const float4*)x;
    float4*       out4 = (float4*)out;

    // channels 0..31: x_j
    out4[(size_t)p * 16 + r] = x4[(size_t)j * 8 + r];

    // channels 32..63: relu(feats @ W + b)
    const float pix = pos[i * 3 + 0], piy = pos[i * 3 + 1], piz = pos[i * 3 + 2];
    const float pjx = pos[j * 3 + 0], pjy = pos[j * 3 + 1], pjz = pos[j * 3 + 2];
    const float rx = pix - pjx, ry = piy - pjy, rz = piz - pjz;
    const float dist = sqrtf(rx * rx + ry * ry + rz * rz + 1e-12f);
    const float f[10] = {pix, piy, piz, pjx, pjy, pjz, rx, ry, rz, dist};

    const float4* W4 = (const float4*)Wm;            // W[10][32]: row = 8 float4
    float4 acc = ((const float4*)bv)[r];
#pragma unroll
    for (int m = 0; m < 10; ++m) {
        const float4 wv = W4[m * 8 + r];
        acc.x = fmaf(f[m], wv.x, acc.x);
        acc.y = fmaf(f[m], wv.y, acc.y);
        acc.z = fmaf(f[m], wv.z, acc.z);
        acc.w = fmaf(f[m], wv.w, acc.w);
    }
    acc.x = fmaxf(acc.x, 0.0f);
    acc.y = fmaxf(acc.y, 0.0f);
    acc.z = fmaxf(acc.z, 0.0f);
    acc.w = fmaxf(acc.w, 0.0f);
    out4[(size_t)p * 16 + 8 + r] = acc;
}

extern "C" void kernel_launch(void* const* d_in, const int* in_sizes, int n_in,
                              void* d_out, int out_size, void* d_ws, size_t ws_size,
                              hipStream_t stream) {
    const float* x   = (const float*)d_in[0];
    const float* pos = (const float*)d_in[1];
    // d_in[2] = batch (unused: equal-size contiguous clouds)
    const float* Wm  = (const float*)d_in[3];
    const float* bv  = (const float*)d_in[4];
    int*   idx = (int*)d_ws;                 // N*K ints = 2 MB scratch
    float* out = (float*)d_out;

    knn_kernel<<<B_ * 32, NTK, 0, stream>>>(pos, idx);

    const int pairs = B_ * S_ * K_;          // 524288
    out_kernel<<<(pairs * 8) / 256, 256, 0, stream>>>(x, pos, Wm, bv, idx, out);
}

// Round 5
// 47.267 us; speedup vs baseline: 7.8838x; 1.3940x over previous
//
#include <hip/hip_runtime.h>

typedef unsigned long long u64;
typedef unsigned int u32;

#define B_  32
#define S_  1024
#define K_  16
#define NTK 256     // threads/block
#define QPB 32      // queries per block (NTK/8)

// key = double whose bit pattern is (d2_f32_bits << 32) | j.
// d2 >= 0 -> high word in [0, 0x7F7FFFFF] -> positive finite double,
// so IEEE fmin/fmax (v_min_f64/v_max_f64) order keys exactly as u64.
__device__ __forceinline__ double pack_key(float d2, int j) {
    return __longlong_as_double(((u64)__float_as_uint(d2) << 32) | (u32)j);
}

// ascending compare-exchange: 2 VALU instrs
__device__ __forceinline__ void ce(double& a, double& b) {
    const double lo = fmin(a, b);
    const double hi = fmax(a, b);
    a = lo; b = hi;
}

// Batcher odd-even mergesort of 8 keys, 19 CE, depth 6, ascending
__device__ __forceinline__ void sort8(double (&k)[8]) {
    ce(k[0], k[1]); ce(k[2], k[3]); ce(k[4], k[5]); ce(k[6], k[7]);
    ce(k[0], k[2]); ce(k[1], k[3]); ce(k[4], k[6]); ce(k[5], k[7]);
    ce(k[1], k[2]); ce(k[5], k[6]);
    ce(k[0], k[4]); ce(k[1], k[5]); ce(k[2], k[6]); ce(k[3], k[7]);
    ce(k[2], k[4]); ce(k[3], k[5]);
    ce(k[1], k[2]); ce(k[3], k[4]); ce(k[5], k[6]);
}

// clean a bitonic 16-sequence into ascending order (4 stages, 32 CE)
__device__ __forceinline__ void clean16(double (&k)[16]) {
#pragma unroll
    for (int str = 8; str > 0; str >>= 1) {
#pragma unroll
        for (int t = 0; t < 16; ++t) {
            const int p = t ^ str;
            if (p > t) ce(k[t], k[p]);
        }
    }
}

__global__ __launch_bounds__(NTK, 4)
void knn_fused(const float* __restrict__ pos, const float* __restrict__ x,
               const float* __restrict__ Wm, const float* __restrict__ bv,
               float* __restrict__ out) {
    __shared__ float4 spos[S_];             // 16 KB

    const int tid   = threadIdx.x;
    const int cloud = blockIdx.x >> 5;      // 32 blocks per cloud
    const int qbase = (blockIdx.x & 31) * QPB;
    const int base  = cloud * S_;

    for (int r = tid; r < S_; r += NTK) {
        const float* p = pos + (size_t)(base + r) * 3;
        spos[r] = make_float4(p[0], p[1], p[2], 0.0f);
    }
    __syncthreads();

    const int s  = tid & 7;                 // slice: j = s (mod 8)
    const int qi = qbase + (tid >> 3);      // query within cloud
    const float4 pi = spos[qi];
    const float pix = pi.x, piy = pi.y, piz = pi.z;

    double key[16];
#pragma unroll
    for (int t = 0; t < 16; ++t)
        key[t] = __longlong_as_double(0x7FEFFFFFFFFFFFFFULL);  // > any real key

    const float4* sp = &spos[s];            // lane slice pointer, stride 8
    float4 buf[8];                          // software-pipelined chunk loads
#pragma unroll
    for (int u = 0; u < 8; ++u) buf[u] = sp[8 * u];

    int jlow = s;                           // local j of buf[0]
    for (int c = 0; c < 16; ++c) {          // 16 chunks x 8 candidates = 128
        double nk[8];
#pragma unroll
        for (int u = 0; u < 8; ++u) {
            // bit-exact numpy chain: no fma, (dx2+dy2)+dz2
            const float dx = __fsub_rn(pix, buf[u].x);
            const float dy = __fsub_rn(piy, buf[u].y);
            const float dz = __fsub_rn(piz, buf[u].z);
            const float d2 = __fadd_rn(
                __fadd_rn(__fmul_rn(dx, dx), __fmul_rn(dy, dy)),
                __fmul_rn(dz, dz));
            nk[u] = pack_key(d2, jlow + 8 * u);
        }
        if (c < 15) {                       // prefetch next chunk during sort
            sp += 64;
#pragma unroll
            for (int u = 0; u < 8; ++u) buf[u] = sp[8 * u];
        }
        jlow += 64;

        sort8(nk);
        // keep-16-smallest: INF-padded bitonic half-merge, then clean
#pragma unroll
        for (int t = 0; t < 8; ++t)
            key[8 + t] = fmin(key[8 + t], nk[7 - t]);
        clean16(key);
    }

    // butterfly merge of the 8 slice lists; afterwards ALL 8 lanes of a
    // group hold the identical ascending top-16 of the query.
#pragma unroll
    for (int r = 1; r <= 4; r <<= 1) {
        double nk[16];
#pragma unroll
        for (int t = 0; t < 16; ++t)
            nk[t] = __shfl_xor(key[15 - t], r, 64);  // reversed partner list
#pragma unroll
        for (int t = 0; t < 16; ++t)
            key[t] = fmin(key[t], nk[t]);            // stride-16 half-cleaner
        clean16(key);
    }

    // ---- fused epilogue: each group of 8 lanes emits its query's 16 rows ----
    const float4* x4 = (const float4*)x;
    const float4* W4 = (const float4*)Wm;   // W[10][32]: row = 8 float4
    float4 wcol[10];
#pragma unroll
    for (int m = 0; m < 10; ++m) wcol[m] = W4[m * 8 + s];
    const float4 bb = ((const float4*)bv)[s];

    float4* orow = (float4*)out + (size_t)(base + qi) * (K_ * 16);
#pragma unroll
    for (int k = 0; k < 16; ++k) {
        const int jl = (int)(u32)__double_as_longlong(key[k]);   // local j
        // channels 4s..4s+3 of x_j (lane-coalesced 128B per group)
        const float4 xj = x4[(size_t)(base + jl) * 8 + s];
        // enc channels 32+4s..32+4s+3
        const float4 pj = spos[jl];                              // broadcast
        const float rx = pix - pj.x, ry = piy - pj.y, rz = piz - pj.z;
        const float dist = sqrtf(rx * rx + ry * ry + rz * rz + 1e-12f);
        const float f[10] = {pix, piy, piz, pj.x, pj.y, pj.z, rx, ry, rz, dist};
        float4 acc = bb;
#pragma unroll
        for (int m = 0; m < 10; ++m) {
            acc.x = fmaf(f[m], wcol[m].x, acc.x);
            acc.y = fmaf(f[m], wcol[m].y, acc.y);
            acc.z = fmaf(f[m], wcol[m].z, acc.z);
            acc.w = fmaf(f[m], wcol[m].w, acc.w);
        }
        acc.x = fmaxf(acc.x, 0.0f);
        acc.y = fmaxf(acc.y, 0.0f);
        acc.z = fmaxf(acc.z, 0.0f);
        acc.w = fmaxf(acc.w, 0.0f);
        orow[k * 16 + s]     = xj;
        orow[k * 16 + 8 + s] = acc;
    }
}

extern "C" void kernel_launch(void* const* d_in, const int* in_sizes, int n_in,
                              void* d_out, int out_size, void* d_ws, size_t ws_size,
                              hipStream_t stream) {
    const float* x   = (const float*)d_in[0];
    const float* pos = (const float*)d_in[1];
    // d_in[2] = batch (unused: equal-size contiguous clouds)
    const float* Wm  = (const float*)d_in[3];
    const float* bv  = (const float*)d_in[4];
    float* out = (float*)d_out;

    knn_fused<<<B_ * 32, NTK, 0, stream>>>(pos, x, Wm, bv, out);
}